// Round 1
// baseline (280.436 us; speedup 1.0000x reference)
//
#include <hip/hip_runtime.h>
#include <stdint.h>

typedef unsigned short u16;
typedef unsigned int   u32;
typedef _Float16       f16;

typedef __attribute__((ext_vector_type(2))) _Float16 half2v;
typedef __attribute__((ext_vector_type(4))) _Float16 half4v;
typedef __attribute__((ext_vector_type(8))) _Float16 half8v;
typedef __attribute__((ext_vector_type(4))) float    floatx4;

#define NXS    512
#define NYS    512
#define NHEAD  8
#define DHEAD  10
#define DMODEL 80
#define DXK    768
#define DYK    283
#define DYKP   288   // padded

__device__ inline half2v pk2(float x, float y) {
  return __builtin_bit_cast(half2v, __builtin_amdgcn_cvt_pkrtz(x, y));
}
__device__ inline half4v cvt4(float4 v) {
  return __builtin_shufflevector(pk2(v.x, v.y), pk2(v.z, v.w), 0, 1, 2, 3);
}
__device__ inline half8v cvt8(float4 a, float4 b) {
  const half4v lo = cvt4(a), hi = cvt4(b);
  return __builtin_shufflevector(lo, hi, 0, 1, 2, 3, 4, 5, 6, 7);
}
__device__ inline half4v h4u32(u32 a, u32 b) {
  return __builtin_shufflevector(__builtin_bit_cast(half2v, a),
                                 __builtin_bit_cast(half2v, b), 0, 1, 2, 3);
}

// =====================================================================
// w_prep: transpose + fp32->f16 weights. Tq[c][k] (80x768),
// Tk/Tv[c][k] (80x288, zero-padded past k=283).
// =====================================================================
__global__ __launch_bounds__(256) void w_prep(const float* __restrict__ Wq,
                                              const float* __restrict__ Wk,
                                              const float* __restrict__ Wv,
                                              f16* __restrict__ Tq,
                                              f16* __restrict__ Tk,
                                              f16* __restrict__ Tv) {
  const int idx = blockIdx.x * 256 + threadIdx.x;
  if (idx < 80 * 768) {
    const int c = idx / 768, k = idx - c * 768;
    Tq[idx] = (f16)Wq[k * 80 + c];
  }
  if (idx < 80 * 288) {
    const int c = idx / 288, k = idx - c * 288;
    float a = 0.f, b = 0.f;
    if (k < DYK) { a = Wk[k * 80 + c]; b = Wv[k * 80 + c]; }
    Tk[idx] = (f16)a;
    Tv[idx] = (f16)b;
  }
}

// =====================================================================
// proj v2: ZERO LDS, ZERO barriers. Weights (f16, pre-transposed) are
// tiny (Wq^T 122KB, Wk/Wv^T 45KB each) and L1/L2-resident broadcast
// data -> read b-fragments straight from global as aligned half8v.
// A-fragments read straight from fp32 X/Y per lane (4 quads cover a
// contiguous 128B row segment -> full cache-line utilization).
// Fully unrolled K loops (all load offsets become immediates), no
// inter-wave coupling, Q/KV blocks interleaved even/odd; with 0 LDS
// and <=128 VGPR the entire 1024-block grid is resident at once.
// =====================================================================
__global__ __launch_bounds__(256, 4) void proj(const float* __restrict__ X,
                                               const float* __restrict__ Y,
                                               const f16* __restrict__ Wtq,
                                               const f16* __restrict__ Wtk,
                                               const f16* __restrict__ Wtv,
                                               f16* __restrict__ Qw,
                                               f16* __restrict__ Kw,
                                               f16* __restrict__ Vw) {
  const int t = threadIdx.x;
  const int wv = t >> 6, lane = t & 63, m16 = lane & 15, quad = lane >> 4;
  const int blk = blockIdx.x;
  const int tile = blk >> 1;
  const int row0 = tile * 64;
  const int row = row0 + wv * 16 + m16;   // a-frag row this lane reads
  const int kq = quad * 8;                // k-phase within a 32-wide step

  if (!(blk & 1)) {
    // ---------------- Q path: 64 rows of X, K=768 (24 steps) ----------------
    const float* xrow = X + (size_t)row * DXK + kq;
    const f16*   wqb  = Wtq + m16 * DXK + kq;

    floatx4 acc[5];
#pragma unroll
    for (int i = 0; i < 5; ++i) acc[i] = (floatx4){0.f, 0.f, 0.f, 0.f};

#pragma unroll
    for (int s = 0; s < 24; ++s) {
      const float4 xa = *(const float4*)(xrow + s * 32);
      const float4 xb = *(const float4*)(xrow + s * 32 + 4);
      const half8v a = cvt8(xa, xb);
#pragma unroll
      for (int nt = 0; nt < 5; ++nt) {
        const half8v b = *(const half8v*)(wqb + nt * 16 * DXK + s * 32);
        acc[nt] = __builtin_amdgcn_mfma_f32_16x16x32_f16(a, b, acc[nt], 0, 0, 0);
      }
    }

#pragma unroll
    for (int nt = 0; nt < 5; ++nt) {
      const int col = nt * 16 + m16;
#pragma unroll
      for (int p = 0; p < 4; ++p) {
        const int grow = row0 + wv * 16 + quad * 4 + p;
        Qw[(size_t)grow * DMODEL + col] = (f16)acc[nt][p];
      }
    }
  } else {
    // ---------------- KV path: 64 rows of Y, K=283->288 (9 steps) ----------------
    const float* yrow = Y + (size_t)row * DYK;
    const f16*   wkb  = Wtk + m16 * DYKP + kq;
    const f16*   wvb  = Wtv + m16 * DYKP + kq;

    floatx4 ak[5], av[5];
#pragma unroll
    for (int i = 0; i < 5; ++i) {
      ak[i] = (floatx4){0.f, 0.f, 0.f, 0.f};
      av[i] = (floatx4){0.f, 0.f, 0.f, 0.f};
    }

#pragma unroll
    for (int s = 0; s < 9; ++s) {
      const int k0 = s * 32 + kq;
      float yr[8];
#pragma unroll
      for (int j = 0; j < 8; ++j)
        yr[j] = (k0 + j < DYK) ? yrow[k0 + j] : 0.f;   // folds away for s<8
      half8v a;
#pragma unroll
      for (int j = 0; j < 8; ++j) a[j] = (f16)yr[j];   // RTN, matches v1 numerics
#pragma unroll
      for (int nt = 0; nt < 5; ++nt) {
        const half8v bk = *(const half8v*)(wkb + nt * 16 * DYKP + s * 32);
        ak[nt] = __builtin_amdgcn_mfma_f32_16x16x32_f16(a, bk, ak[nt], 0, 0, 0);
        const half8v bv = *(const half8v*)(wvb + nt * 16 * DYKP + s * 32);
        av[nt] = __builtin_amdgcn_mfma_f32_16x16x32_f16(a, bv, av[nt], 0, 0, 0);
      }
    }

#pragma unroll
    for (int nt = 0; nt < 5; ++nt) {
      const int col = nt * 16 + m16;
      const int h = col / 10, d = col - h * 10;
#pragma unroll
      for (int p = 0; p < 4; ++p) {
        const int grow = row0 + wv * 16 + quad * 4 + p;
        const int bb = grow >> 9, ny = grow & 511;
        const size_t o = (((size_t)bb * NHEAD + h) * NYS + ny) * DHEAD + d;
        Kw[o] = (f16)ak[nt][p];
        Vw[o] = (f16)av[nt][p];
      }
    }
  }
}

// =====================================================================
// attn: 2 blocks per (b,h) (grid 1024), 4 waves, 4 q-tiles/wave.
// K,V^T in LDS (odd-dword strides 22 / 522 -> <=2-way bank aliasing);
// Q fragments + residual direct from global. Dual accumulators break
// the oacc MFMA dependency chain. No-max softmax, q pre-scaled.
// =====================================================================
__global__ __launch_bounds__(256) void attn(const f16* __restrict__ Q,
                                            const f16* __restrict__ K,
                                            const f16* __restrict__ V,
                                            float* __restrict__ O) {
  __shared__ f16 Ks[512 * 22];   // [key][d], d 10..15 zeroed
  __shared__ f16 Vt[16 * 522];   // [d][key], d rows 10..15 zeroed
  const int t = threadIdx.x;
  const int wv = t >> 6, lane = t & 63, m16 = lane & 15, quad = lane >> 4;
  const int bh = blockIdx.x >> 1, half = blockIdx.x & 1;
  const int b = bh >> 3, h = bh & 7;

  const u32* Kg = (const u32*)K + (size_t)bh * NYS * 5;
  const u32* Vg = (const u32*)V + (size_t)bh * NYS * 5;
  for (int idx = t; idx < 2560; idx += 256) {
    const u32 row = (u32)idx / 5u, c = (u32)idx - row * 5u;
    const half2v kv = __builtin_bit_cast(half2v, Kg[idx]);
    Ks[row * 22 + 2 * c]     = kv[0];
    Ks[row * 22 + 2 * c + 1] = kv[1];
    const half2v vvv = __builtin_bit_cast(half2v, Vg[idx]);
    Vt[(2 * c) * 522 + row]     = vvv[0];
    Vt[(2 * c + 1) * 522 + row] = vvv[1];
  }
  for (int idx = t; idx < 3072; idx += 256) {  // Ks d-pad 10..15
    const u32 row = (u32)idx / 6u, d = 10u + ((u32)idx - row * 6u);
    Ks[row * 22 + d] = (f16)0.f;
  }
  for (int idx = t; idx < 6 * 522; idx += 256)  // Vt rows 10..15
    Vt[10 * 522 + idx] = (f16)0.f;
  __syncthreads();

  const float scale = 0.31622776601683794f;  // 1/sqrt(10)
#pragma unroll 1
  for (int i = 0; i < 4; ++i) {
    const int qt = half * 16 + wv * 4 + i;
    const int qrow = qt * 16 + m16;
    const u32* Qg32 = (const u32*)(Q + ((size_t)b * NXS + qrow) * DMODEL + h * DHEAD);
    float s0 = 0.f, s1 = 0.f, s2 = 0.f, s3 = 0.f;
    if (quad < 2) {
      const u32 ua = Qg32[quad * 2], ub = Qg32[quad * 2 + 1];
      const half2v ha = __builtin_bit_cast(half2v, ua);
      const half2v hb = __builtin_bit_cast(half2v, ub);
      s0 = (float)ha[0]; s1 = (float)ha[1]; s2 = (float)hb[0]; s3 = (float)hb[1];
    } else if (quad == 2) {
      const u32 ua = Qg32[4];
      const half2v ha = __builtin_bit_cast(half2v, ua);
      s0 = (float)ha[0]; s1 = (float)ha[1];
    }
    const half4v qf = __builtin_shufflevector(pk2(s0 * scale, s1 * scale),
                                              pk2(s2 * scale, s3 * scale),
                                              0, 1, 2, 3);
    floatx4 o0 = (floatx4){0.f, 0.f, 0.f, 0.f};
    floatx4 o1 = (floatx4){0.f, 0.f, 0.f, 0.f};
    float l0 = 0.f, l1 = 0.f;
    for (int kt = 0; kt < 32; kt += 2) {
#pragma unroll
      for (int u = 0; u < 2; ++u) {
        const int ktu = kt + u;
        const int kb = (ktu * 16 + m16) * 22 + quad * 4;
        const half4v kf = h4u32(*(const u32*)&Ks[kb], *(const u32*)&Ks[kb + 2]);
        const floatx4 s = __builtin_amdgcn_mfma_f32_16x16x16f16(
            kf, qf, (floatx4){0.f, 0.f, 0.f, 0.f}, 0, 0, 0);
        const float p0 = __expf(s[0]);
        const float p1 = __expf(s[1]);
        const float p2 = __expf(s[2]);
        const float p3 = __expf(s[3]);
        const half4v pf = __builtin_shufflevector(pk2(p0, p1), pk2(p2, p3),
                                                  0, 1, 2, 3);
        const int vb = m16 * 522 + ktu * 16 + quad * 4;
        const half4v vf = h4u32(*(const u32*)&Vt[vb], *(const u32*)&Vt[vb + 2]);
        if (u == 0) {
          l0 += (p0 + p1) + (p2 + p3);
          o0 = __builtin_amdgcn_mfma_f32_16x16x16f16(pf, vf, o0, 0, 0, 0);
        } else {
          l1 += (p0 + p1) + (p2 + p3);
          o1 = __builtin_amdgcn_mfma_f32_16x16x16f16(pf, vf, o1, 0, 0, 0);
        }
      }
    }
    float lp = l0 + l1;
    lp += __shfl_xor(lp, 16);
    lp += __shfl_xor(lp, 32);
#pragma unroll
    for (int p = 0; p < 4; ++p) {
      const int rq = qt * 16 + quad * 4 + p;
      const float lr = __shfl(lp, quad * 4 + p);
      if (m16 < DHEAD) {
        const float qres = (float)Q[((size_t)b * NXS + rq) * DMODEL + h * DHEAD + m16];
        O[((size_t)b * NXS + rq) * DMODEL + h * DHEAD + m16] =
            qres + (o0[p] + o1[p]) / lr;
      }
    }
  }
}

extern "C" void kernel_launch(void* const* d_in, const int* in_sizes, int n_in,
                              void* d_out, int out_size, void* d_ws, size_t ws_size,
                              hipStream_t stream) {
  const float* x  = (const float*)d_in[0];
  const float* y  = (const float*)d_in[1];
  const float* Wq = (const float*)d_in[2];
  const float* Wk = (const float*)d_in[3];
  const float* Wv = (const float*)d_in[4];
  float* out = (float*)d_out;

  char* ws = (char*)d_ws;
  f16* Wtq = (f16*)(ws);                  // 80*768*2  = 122880 B
  f16* Wtk = (f16*)(ws + 122880);         // 80*288*2  =  46080 B
  f16* Wtv = (f16*)(ws + 168960);         // 46080 B
  f16* Qw  = (f16*)(ws + 262144);         // 5242880 B
  f16* Kw  = (f16*)(ws + 5505024);
  f16* Vw  = (f16*)(ws + 10747904);

  w_prep<<<240, 256, 0, stream>>>(Wq, Wk, Wv, Wtq, Wtk, Wtv);
  proj  <<<1024, 256, 0, stream>>>(x, y, Wtq, Wtk, Wtv, Qw, Kw, Vw);
  attn  <<<1024, 256, 0, stream>>>(Qw, Kw, Vw, out);
}

// Round 2
// 274.636 us; speedup vs baseline: 1.0211x; 1.0211x over previous
//
#include <hip/hip_runtime.h>
#include <stdint.h>

typedef unsigned short u16;
typedef unsigned int   u32;
typedef _Float16       f16;

typedef __attribute__((ext_vector_type(2))) _Float16 half2v;
typedef __attribute__((ext_vector_type(4))) _Float16 half4v;
typedef __attribute__((ext_vector_type(8))) _Float16 half8v;
typedef __attribute__((ext_vector_type(4))) float    floatx4;

#define NXS    512
#define NYS    512
#define NHEAD  8
#define DHEAD  10
#define DMODEL 80
#define DXK    768
#define DYK    283
#define DYKP   320   // padded to 5*64

__device__ inline half2v pk2(float x, float y) {
  return __builtin_bit_cast(half2v, __builtin_amdgcn_cvt_pkrtz(x, y));
}
__device__ inline half4v cvt4(float4 v) {
  return __builtin_shufflevector(pk2(v.x, v.y), pk2(v.z, v.w), 0, 1, 2, 3);
}
__device__ inline half4v h4u32(u32 a, u32 b) {
  return __builtin_shufflevector(__builtin_bit_cast(half2v, a),
                                 __builtin_bit_cast(half2v, b), 0, 1, 2, 3);
}

// =====================================================================
// w_prep v2: COALESCED reads (flat over the source), scattered f16
// stores (fire-and-forget, no latency stall). Tq[c][k] 80x768,
// Tk/Tv[c][k] 80x320 zero-padded past k=283.
// =====================================================================
__global__ __launch_bounds__(256) void w_prep(const float* __restrict__ Wq,
                                              const float* __restrict__ Wk,
                                              const float* __restrict__ Wv,
                                              f16* __restrict__ Tq,
                                              f16* __restrict__ Tk,
                                              f16* __restrict__ Tv) {
  const int i = blockIdx.x * 256 + threadIdx.x;
  if (i < 768 * 80) {              // Wq flat: i = k*80 + c (coalesced read)
    const int k = i / 80, c = i - k * 80;
    Tq[c * DXK + k] = (f16)Wq[i];
  }
  if (i < 283 * 80) {              // Wk/Wv flat
    const int k = i / 80, c = i - k * 80;
    Tk[c * DYKP + k] = (f16)Wk[i];
    Tv[c * DYKP + k] = (f16)Wv[i];
  }
  if (i < 80 * 37) {               // zero pad k in [283,320)
    const int c = i / 37, k = DYK + (i - c * 37);
    Tk[c * DYKP + k] = (f16)0.f;
    Tv[c * DYKP + k] = (f16)0.f;
  }
}

// =====================================================================
// proj v3: v1's staged structure with the stall arithmetic fixed.
//  - BK=64: Q 12 steps (was 24), KV 5 steps (was 9) -> half the barriers,
//    2x MFMA per stall window (10 / 20 MFMAs per wave per step).
//  - X/Y prefetched 2 STEPS ahead (covers ~900cy HBM latency);
//    W prefetched 1 step ahead (L2-hot broadcast, ~200cy).
//  - LDS explicitly UNIONED across Q/KV branches: 32.3 KB (branch-scoped
//    arrays in v1 got summed) -> >=4 blocks/CU.
//  - Q/KV blocks interleaved even/odd so short KV blocks retire under
//    the long Q blocks' shadow on every CU.
//  - Strides 72 f16 = 144 B = 36 dwords: 16B-aligned for b128, rows 0..7
//    cover all 32 banks -> 2-way aliasing (free).
// =====================================================================
__global__ __launch_bounds__(256, 4) void proj(const float* __restrict__ X,
                                               const float* __restrict__ Y,
                                               const f16* __restrict__ Wtq,
                                               const f16* __restrict__ Wtk,
                                               const f16* __restrict__ Wtv,
                                               f16* __restrict__ Qw,
                                               f16* __restrict__ Kw,
                                               f16* __restrict__ Vw) {
  __shared__ f16 smem[64 * 72 + 2 * 80 * 72];   // 32256 B (union of Q/KV layouts)
  const int t = threadIdx.x;
  const int wv = t >> 6, lane = t & 63, m16 = lane & 15, quad = lane >> 4;
  const int blk = blockIdx.x;
  const int row0 = (blk >> 1) * 64;
  const int u0 = t, u1 = t + 256, u2 = t + 512;  // W stage chunks (row=u>>3, ch=u&7)

  if (!(blk & 1)) {
    // ---------------- Q path: 64 rows of X, K=768, 12 steps of 64 ----------------
    f16* Xs = smem;               // [64][72]
    f16* Ws = smem + 64 * 72;     // [80][72]
    const float* Xb = X + (size_t)row0 * DXK;

    float4 xb0[4], xb1[4];
    uint4 wb0, wb1, wb2;
#pragma unroll
    for (int i = 0; i < 4; ++i) {
      const int vi = t + 256 * i;
      xb0[i] = *(const float4*)&Xb[(vi >> 4) * DXK + (vi & 15) * 4];
    }
#pragma unroll
    for (int i = 0; i < 4; ++i) {
      const int vi = t + 256 * i;
      xb1[i] = *(const float4*)&Xb[(vi >> 4) * DXK + 64 + (vi & 15) * 4];
    }
    wb0 = *(const uint4*)&Wtq[(u0 >> 3) * DXK + (u0 & 7) * 8];
    wb1 = *(const uint4*)&Wtq[(u1 >> 3) * DXK + (u1 & 7) * 8];
    if (t < 128) wb2 = *(const uint4*)&Wtq[(u2 >> 3) * DXK + (u2 & 7) * 8];

    floatx4 acc[5];
#pragma unroll
    for (int i = 0; i < 5; ++i) acc[i] = (floatx4){0.f, 0.f, 0.f, 0.f};

#define Q_STORE_LDS(XB)                                                        \
    do {                                                                       \
      _Pragma("unroll")                                                        \
      for (int i = 0; i < 4; ++i) {                                            \
        const int vi = t + 256 * i;                                            \
        *(half4v*)&Xs[(vi >> 4) * 72 + (vi & 15) * 4] = cvt4(XB[i]);           \
      }                                                                        \
      *(uint4*)&Ws[(u0 >> 3) * 72 + (u0 & 7) * 8] = wb0;                       \
      *(uint4*)&Ws[(u1 >> 3) * 72 + (u1 & 7) * 8] = wb1;                       \
      if (t < 128) *(uint4*)&Ws[(u2 >> 3) * 72 + (u2 & 7) * 8] = wb2;          \
    } while (0)

#define Q_LOAD_X(XB, S)                                                        \
    do {                                                                       \
      const int k0_ = (S) * 64;                                                \
      _Pragma("unroll")                                                        \
      for (int i = 0; i < 4; ++i) {                                            \
        const int vi = t + 256 * i;                                            \
        XB[i] = *(const float4*)&Xb[(vi >> 4) * DXK + k0_ + (vi & 15) * 4];    \
      }                                                                        \
    } while (0)

#define Q_LOAD_W(S)                                                            \
    do {                                                                       \
      const int k0_ = (S) * 64;                                                \
      wb0 = *(const uint4*)&Wtq[(u0 >> 3) * DXK + k0_ + (u0 & 7) * 8];         \
      wb1 = *(const uint4*)&Wtq[(u1 >> 3) * DXK + k0_ + (u1 & 7) * 8];         \
      if (t < 128) wb2 = *(const uint4*)&Wtq[(u2 >> 3) * DXK + k0_ + (u2 & 7) * 8]; \
    } while (0)

#define Q_COMPUTE()                                                            \
    do {                                                                       \
      _Pragma("unroll")                                                        \
      for (int kk = 0; kk < 2; ++kk) {                                         \
        const half8v a = *(const half8v*)&Xs[(wv * 16 + m16) * 72 + kk * 32 + quad * 8]; \
        _Pragma("unroll")                                                      \
        for (int nt = 0; nt < 5; ++nt) {                                       \
          const half8v b = *(const half8v*)&Ws[(nt * 16 + m16) * 72 + kk * 32 + quad * 8]; \
          acc[nt] = __builtin_amdgcn_mfma_f32_16x16x32_f16(a, b, acc[nt], 0, 0, 0); \
        }                                                                      \
      }                                                                        \
    } while (0)

    for (int s = 0; s < 12; s += 2) {
      // ---- even step s: LDS holds step s from xb0/wb ----
      if (s) __syncthreads();
      Q_STORE_LDS(xb0);
      __syncthreads();
      if (s + 2 < 12) Q_LOAD_X(xb0, s + 2);
      Q_LOAD_W(s + 1);
      Q_COMPUTE();
      // ---- odd step s+1: from xb1/wb ----
      __syncthreads();
      Q_STORE_LDS(xb1);
      __syncthreads();
      if (s + 3 < 12) Q_LOAD_X(xb1, s + 3);
      if (s + 2 < 12) Q_LOAD_W(s + 2);
      Q_COMPUTE();
    }

#pragma unroll
    for (int nt = 0; nt < 5; ++nt) {
      const int col = nt * 16 + m16;
#pragma unroll
      for (int p = 0; p < 4; ++p) {
        const int grow = row0 + wv * 16 + quad * 4 + p;
        Qw[(size_t)grow * DMODEL + col] = (f16)acc[nt][p];
      }
    }
  } else {
    // ---------------- KV path: 64 rows of Y, K=283->320, 5 steps of 64 ----------------
    f16* Ys  = smem;                        // [64][72]
    f16* Wks = smem + 64 * 72;              // [80][72]
    f16* Wvs = smem + 64 * 72 + 80 * 72;    // [80][72]
    const float* Yb = Y + (size_t)row0 * DYK;

    float yb[2][16];
    uint4 wk0, wk1, wk2, wvr0, wvr1, wvr2;

#define KV_LOAD_Y(BI, S)                                                       \
    do {                                                                       \
      _Pragma("unroll")                                                        \
      for (int i = 0; i < 16; ++i) {                                           \
        const int idx = t + 256 * i;                                           \
        const int r = idx >> 6, kk = idx & 63;                                 \
        const int k = (S) * 64 + kk;                                           \
        yb[BI][i] = (k < DYK) ? Yb[(size_t)r * DYK + k] : 0.f;                 \
      }                                                                        \
    } while (0)

#define KV_LOAD_W(S)                                                           \
    do {                                                                       \
      const int k0_ = (S) * 64;                                                \
      wk0 = *(const uint4*)&Wtk[(u0 >> 3) * DYKP + k0_ + (u0 & 7) * 8];        \
      wk1 = *(const uint4*)&Wtk[(u1 >> 3) * DYKP + k0_ + (u1 & 7) * 8];        \
      wvr0 = *(const uint4*)&Wtv[(u0 >> 3) * DYKP + k0_ + (u0 & 7) * 8];       \
      wvr1 = *(const uint4*)&Wtv[(u1 >> 3) * DYKP + k0_ + (u1 & 7) * 8];       \
      if (t < 128) {                                                           \
        wk2  = *(const uint4*)&Wtk[(u2 >> 3) * DYKP + k0_ + (u2 & 7) * 8];     \
        wvr2 = *(const uint4*)&Wtv[(u2 >> 3) * DYKP + k0_ + (u2 & 7) * 8];     \
      }                                                                        \
    } while (0)

    KV_LOAD_Y(0, 0);
    KV_LOAD_Y(1, 1);
    KV_LOAD_W(0);

    floatx4 ak[5], av[5];
#pragma unroll
    for (int i = 0; i < 5; ++i) {
      ak[i] = (floatx4){0.f, 0.f, 0.f, 0.f};
      av[i] = (floatx4){0.f, 0.f, 0.f, 0.f};
    }

#pragma unroll
    for (int s = 0; s < 5; ++s) {
      if (s) __syncthreads();
#pragma unroll
      for (int i = 0; i < 16; ++i) {
        const int idx = t + 256 * i;
        Ys[(idx >> 6) * 72 + (idx & 63)] = (f16)yb[s & 1][i];
      }
      *(uint4*)&Wks[(u0 >> 3) * 72 + (u0 & 7) * 8] = wk0;
      *(uint4*)&Wks[(u1 >> 3) * 72 + (u1 & 7) * 8] = wk1;
      *(uint4*)&Wvs[(u0 >> 3) * 72 + (u0 & 7) * 8] = wvr0;
      *(uint4*)&Wvs[(u1 >> 3) * 72 + (u1 & 7) * 8] = wvr1;
      if (t < 128) {
        *(uint4*)&Wks[(u2 >> 3) * 72 + (u2 & 7) * 8] = wk2;
        *(uint4*)&Wvs[(u2 >> 3) * 72 + (u2 & 7) * 8] = wvr2;
      }
      __syncthreads();
      if (s + 2 < 5) KV_LOAD_Y(s & 1, s + 2);
      if (s + 1 < 5) KV_LOAD_W(s + 1);
#pragma unroll
      for (int kk = 0; kk < 2; ++kk) {
        const half8v a = *(const half8v*)&Ys[(wv * 16 + m16) * 72 + kk * 32 + quad * 8];
#pragma unroll
        for (int nt = 0; nt < 5; ++nt) {
          const half8v bk = *(const half8v*)&Wks[(nt * 16 + m16) * 72 + kk * 32 + quad * 8];
          ak[nt] = __builtin_amdgcn_mfma_f32_16x16x32_f16(a, bk, ak[nt], 0, 0, 0);
          const half8v bv = *(const half8v*)&Wvs[(nt * 16 + m16) * 72 + kk * 32 + quad * 8];
          av[nt] = __builtin_amdgcn_mfma_f32_16x16x32_f16(a, bv, av[nt], 0, 0, 0);
        }
      }
    }

#pragma unroll
    for (int nt = 0; nt < 5; ++nt) {
      const int col = nt * 16 + m16;
      const int h = col / 10, d = col - h * 10;
#pragma unroll
      for (int p = 0; p < 4; ++p) {
        const int grow = row0 + wv * 16 + quad * 4 + p;
        const int bb = grow >> 9, ny = grow & 511;
        const size_t o = (((size_t)bb * NHEAD + h) * NYS + ny) * DHEAD + d;
        Kw[o] = (f16)ak[nt][p];
        Vw[o] = (f16)av[nt][p];
      }
    }
  }
}

// =====================================================================
// attn: unchanged. 2 blocks per (b,h) (grid 1024), 4 waves, 4 q-tiles/wave.
// K,V^T in LDS (odd-dword strides 22 / 522); Q frags + residual direct
// from global. Dual accumulators; no-max softmax, q pre-scaled.
// =====================================================================
__global__ __launch_bounds__(256) void attn(const f16* __restrict__ Q,
                                            const f16* __restrict__ K,
                                            const f16* __restrict__ V,
                                            float* __restrict__ O) {
  __shared__ f16 Ks[512 * 22];   // [key][d], d 10..15 zeroed
  __shared__ f16 Vt[16 * 522];   // [d][key], d rows 10..15 zeroed
  const int t = threadIdx.x;
  const int wv = t >> 6, lane = t & 63, m16 = lane & 15, quad = lane >> 4;
  const int bh = blockIdx.x >> 1, half = blockIdx.x & 1;
  const int b = bh >> 3, h = bh & 7;

  const u32* Kg = (const u32*)K + (size_t)bh * NYS * 5;
  const u32* Vg = (const u32*)V + (size_t)bh * NYS * 5;
  for (int idx = t; idx < 2560; idx += 256) {
    const u32 row = (u32)idx / 5u, c = (u32)idx - row * 5u;
    const half2v kv = __builtin_bit_cast(half2v, Kg[idx]);
    Ks[row * 22 + 2 * c]     = kv[0];
    Ks[row * 22 + 2 * c + 1] = kv[1];
    const half2v vvv = __builtin_bit_cast(half2v, Vg[idx]);
    Vt[(2 * c) * 522 + row]     = vvv[0];
    Vt[(2 * c + 1) * 522 + row] = vvv[1];
  }
  for (int idx = t; idx < 3072; idx += 256) {  // Ks d-pad 10..15
    const u32 row = (u32)idx / 6u, d = 10u + ((u32)idx - row * 6u);
    Ks[row * 22 + d] = (f16)0.f;
  }
  for (int idx = t; idx < 6 * 522; idx += 256)  // Vt rows 10..15
    Vt[10 * 522 + idx] = (f16)0.f;
  __syncthreads();

  const float scale = 0.31622776601683794f;  // 1/sqrt(10)
#pragma unroll 1
  for (int i = 0; i < 4; ++i) {
    const int qt = half * 16 + wv * 4 + i;
    const int qrow = qt * 16 + m16;
    const u32* Qg32 = (const u32*)(Q + ((size_t)b * NXS + qrow) * DMODEL + h * DHEAD);
    float s0 = 0.f, s1 = 0.f, s2 = 0.f, s3 = 0.f;
    if (quad < 2) {
      const u32 ua = Qg32[quad * 2], ub = Qg32[quad * 2 + 1];
      const half2v ha = __builtin_bit_cast(half2v, ua);
      const half2v hb = __builtin_bit_cast(half2v, ub);
      s0 = (float)ha[0]; s1 = (float)ha[1]; s2 = (float)hb[0]; s3 = (float)hb[1];
    } else if (quad == 2) {
      const u32 ua = Qg32[4];
      const half2v ha = __builtin_bit_cast(half2v, ua);
      s0 = (float)ha[0]; s1 = (float)ha[1];
    }
    const half4v qf = __builtin_shufflevector(pk2(s0 * scale, s1 * scale),
                                              pk2(s2 * scale, s3 * scale),
                                              0, 1, 2, 3);
    floatx4 o0 = (floatx4){0.f, 0.f, 0.f, 0.f};
    floatx4 o1 = (floatx4){0.f, 0.f, 0.f, 0.f};
    float l0 = 0.f, l1 = 0.f;
    for (int kt = 0; kt < 32; kt += 2) {
#pragma unroll
      for (int u = 0; u < 2; ++u) {
        const int ktu = kt + u;
        const int kb = (ktu * 16 + m16) * 22 + quad * 4;
        const half4v kf = h4u32(*(const u32*)&Ks[kb], *(const u32*)&Ks[kb + 2]);
        const floatx4 s = __builtin_amdgcn_mfma_f32_16x16x16f16(
            kf, qf, (floatx4){0.f, 0.f, 0.f, 0.f}, 0, 0, 0);
        const float p0 = __expf(s[0]);
        const float p1 = __expf(s[1]);
        const float p2 = __expf(s[2]);
        const float p3 = __expf(s[3]);
        const half4v pf = __builtin_shufflevector(pk2(p0, p1), pk2(p2, p3),
                                                  0, 1, 2, 3);
        const int vb = m16 * 522 + ktu * 16 + quad * 4;
        const half4v vf = h4u32(*(const u32*)&Vt[vb], *(const u32*)&Vt[vb + 2]);
        if (u == 0) {
          l0 += (p0 + p1) + (p2 + p3);
          o0 = __builtin_amdgcn_mfma_f32_16x16x16f16(pf, vf, o0, 0, 0, 0);
        } else {
          l1 += (p0 + p1) + (p2 + p3);
          o1 = __builtin_amdgcn_mfma_f32_16x16x16f16(pf, vf, o1, 0, 0, 0);
        }
      }
    }
    float lp = l0 + l1;
    lp += __shfl_xor(lp, 16);
    lp += __shfl_xor(lp, 32);
#pragma unroll
    for (int p = 0; p < 4; ++p) {
      const int rq = qt * 16 + quad * 4 + p;
      const float lr = __shfl(lp, quad * 4 + p);
      if (m16 < DHEAD) {
        const float qres = (float)Q[((size_t)b * NXS + rq) * DMODEL + h * DHEAD + m16];
        O[((size_t)b * NXS + rq) * DMODEL + h * DHEAD + m16] =
            qres + (o0[p] + o1[p]) / lr;
      }
    }
  }
}

extern "C" void kernel_launch(void* const* d_in, const int* in_sizes, int n_in,
                              void* d_out, int out_size, void* d_ws, size_t ws_size,
                              hipStream_t stream) {
  const float* x  = (const float*)d_in[0];
  const float* y  = (const float*)d_in[1];
  const float* Wq = (const float*)d_in[2];
  const float* Wk = (const float*)d_in[3];
  const float* Wv = (const float*)d_in[4];
  float* out = (float*)d_out;

  char* ws = (char*)d_ws;
  f16* Wtq = (f16*)(ws);                  // 80*768*2  = 122880 B
  f16* Wtk = (f16*)(ws + 122880);         // 80*320*2  =  51200 B
  f16* Wtv = (f16*)(ws + 174080);         // 51200 B -> ends 225280
  f16* Qw  = (f16*)(ws + 262144);         // 5242880 B
  f16* Kw  = (f16*)(ws + 5505024);
  f16* Vw  = (f16*)(ws + 10747904);

  w_prep<<<240, 256, 0, stream>>>(Wq, Wk, Wv, Wtq, Wtk, Wtv);
  proj  <<<1024, 256, 0, stream>>>(x, y, Wtq, Wtk, Wtv, Qw, Kw, Vw);
  attn  <<<1024, 256, 0, stream>>>(Qw, Kw, Vw, out);
}

// Round 3
// 255.868 us; speedup vs baseline: 1.0960x; 1.0733x over previous
//
#include <hip/hip_runtime.h>
#include <stdint.h>

typedef unsigned short u16;
typedef unsigned int   u32;
typedef _Float16       f16;

typedef __attribute__((ext_vector_type(2))) _Float16 half2v;
typedef __attribute__((ext_vector_type(4))) _Float16 half4v;
typedef __attribute__((ext_vector_type(8))) _Float16 half8v;
typedef __attribute__((ext_vector_type(4))) float    floatx4;

#define NXS    512
#define NYS    512
#define NHEAD  8
#define DHEAD  10
#define DMODEL 80
#define DXK    768
#define DYK    283
#define DYKP   288   // padded

__device__ inline half2v pk2(float x, float y) {
  return __builtin_bit_cast(half2v, __builtin_amdgcn_cvt_pkrtz(x, y));
}
__device__ inline half4v cvt4(float4 v) {
  return __builtin_shufflevector(pk2(v.x, v.y), pk2(v.z, v.w), 0, 1, 2, 3);
}
__device__ inline half4v h4u32(u32 a, u32 b) {
  return __builtin_shufflevector(__builtin_bit_cast(half2v, a),
                                 __builtin_bit_cast(half2v, b), 0, 1, 2, 3);
}

// =====================================================================
// w_prep: transpose + fp32->f16 weights. Tq[c][k] (80x768),
// Tk/Tv[c][k] (80x288, zero-padded past k=283).  (v1 exact)
// =====================================================================
__global__ __launch_bounds__(256) void w_prep(const float* __restrict__ Wq,
                                              const float* __restrict__ Wk,
                                              const float* __restrict__ Wv,
                                              f16* __restrict__ Tq,
                                              f16* __restrict__ Tk,
                                              f16* __restrict__ Tv) {
  const int idx = blockIdx.x * 256 + threadIdx.x;
  if (idx < 80 * 768) {
    const int c = idx / 768, k = idx - c * 768;
    Tq[idx] = (f16)Wq[k * 80 + c];
  }
  if (idx < 80 * 288) {
    const int c = idx / 288, k = idx - c * 288;
    float a = 0.f, b = 0.f;
    if (k < DYK) { a = Wk[k * 80 + c]; b = Wv[k * 80 + c]; }
    Tk[idx] = (f16)a;
    Tv[idx] = (f16)b;
  }
}

// =====================================================================
// proj: v1 structure EXACTLY (LDS-staged, 1-step register prefetch,
// coalesced loads). Single change vs v1: Q/KV selected by (blk & 1)
// instead of blk<512, so every CU gets a mix of long Q blocks (24
// steps) and short KV blocks (9 steps) -> no idle-CU tail.
// =====================================================================
__global__ __launch_bounds__(256) void proj(const float* __restrict__ X,
                                            const float* __restrict__ Y,
                                            const f16* __restrict__ Wtq,
                                            const f16* __restrict__ Wtk,
                                            const f16* __restrict__ Wtv,
                                            f16* __restrict__ Qw,
                                            f16* __restrict__ Kw,
                                            f16* __restrict__ Vw) {
  const int t = threadIdx.x;
  const int wv = t >> 6, lane = t & 63, m16 = lane & 15, quad = lane >> 4;
  const int blk = blockIdx.x;
  const int row0 = (blk >> 1) * 64;

  if (!(blk & 1)) {
    // ---------------- Q path ----------------
    __shared__ f16 Xs[64 * 40];
    __shared__ f16 Ws[80 * 40];
    const int xr_r = t >> 3, xr_k = (t & 7) << 2;   // rows 0..31, +32 pair
    const int wi0 = t, wi1 = t + 160;

    float4 xr0, xr1;
    uint4 wr0, wr1;
    xr0 = *(const float4*)&X[(size_t)(row0 + xr_r) * DXK + xr_k];
    xr1 = *(const float4*)&X[(size_t)(row0 + xr_r + 32) * DXK + xr_k];
    if (t < 160) {
      wr0 = *(const uint4*)&Wtq[(wi0 >> 2) * DXK + (wi0 & 3) * 8];
      wr1 = *(const uint4*)&Wtq[(wi1 >> 2) * DXK + (wi1 & 3) * 8];
    }

    floatx4 acc[5];
#pragma unroll
    for (int i = 0; i < 5; ++i) acc[i] = (floatx4){0.f, 0.f, 0.f, 0.f};

    for (int s = 0; s < 24; ++s) {
      if (s) __syncthreads();
      *(half4v*)&Xs[xr_r * 40 + xr_k] = cvt4(xr0);
      *(half4v*)&Xs[(xr_r + 32) * 40 + xr_k] = cvt4(xr1);
      if (t < 160) {
        *(uint4*)&Ws[(wi0 >> 2) * 40 + (wi0 & 3) * 8] = wr0;
        *(uint4*)&Ws[(wi1 >> 2) * 40 + (wi1 & 3) * 8] = wr1;
      }
      __syncthreads();
      if (s < 23) {
        const int k0 = (s + 1) * 32;
        xr0 = *(const float4*)&X[(size_t)(row0 + xr_r) * DXK + k0 + xr_k];
        xr1 = *(const float4*)&X[(size_t)(row0 + xr_r + 32) * DXK + k0 + xr_k];
        if (t < 160) {
          wr0 = *(const uint4*)&Wtq[(wi0 >> 2) * DXK + k0 + (wi0 & 3) * 8];
          wr1 = *(const uint4*)&Wtq[(wi1 >> 2) * DXK + k0 + (wi1 & 3) * 8];
        }
      }
      const half8v a = *(const half8v*)&Xs[(wv * 16 + m16) * 40 + quad * 8];
#pragma unroll
      for (int nt = 0; nt < 5; ++nt) {
        const half8v b = *(const half8v*)&Ws[(nt * 16 + m16) * 40 + quad * 8];
        acc[nt] = __builtin_amdgcn_mfma_f32_16x16x32_f16(a, b, acc[nt], 0, 0, 0);
      }
    }
#pragma unroll
    for (int nt = 0; nt < 5; ++nt) {
      const int col = nt * 16 + m16;
#pragma unroll
      for (int p = 0; p < 4; ++p) {
        const int grow = row0 + wv * 16 + quad * 4 + p;
        Qw[(size_t)grow * DMODEL + col] = (f16)acc[nt][p];
      }
    }
  } else {
    // ---------------- KV path ----------------
    __shared__ f16 Ys[64 * 40];
    __shared__ f16 Wks[80 * 40];
    __shared__ f16 Wvs[80 * 40];
    const int wi0 = t, wi1 = t + 160;

    float yr[8];
    uint4 wk0, wk1, wv0, wv1;
#pragma unroll
    for (int i = 0; i < 8; ++i) {
      const int idx = t + 256 * i;                  // consecutive t -> consecutive k
      const int r = idx >> 5, kk = idx & 31;
      yr[i] = Y[(size_t)(row0 + r) * DYK + kk];
    }
    if (t < 160) {
      wk0 = *(const uint4*)&Wtk[(wi0 >> 2) * DYKP + (wi0 & 3) * 8];
      wk1 = *(const uint4*)&Wtk[(wi1 >> 2) * DYKP + (wi1 & 3) * 8];
      wv0 = *(const uint4*)&Wtv[(wi0 >> 2) * DYKP + (wi0 & 3) * 8];
      wv1 = *(const uint4*)&Wtv[(wi1 >> 2) * DYKP + (wi1 & 3) * 8];
    }

    floatx4 ak[5], av[5];
#pragma unroll
    for (int i = 0; i < 5; ++i) {
      ak[i] = (floatx4){0.f, 0.f, 0.f, 0.f};
      av[i] = (floatx4){0.f, 0.f, 0.f, 0.f};
    }

    for (int s = 0; s < 9; ++s) {   // 288/32
      if (s) __syncthreads();
#pragma unroll
      for (int i = 0; i < 8; ++i) {
        const int idx = t + 256 * i;
        Ys[(idx >> 5) * 40 + (idx & 31)] = (f16)yr[i];
      }
      if (t < 160) {
        *(uint4*)&Wks[(wi0 >> 2) * 40 + (wi0 & 3) * 8] = wk0;
        *(uint4*)&Wks[(wi1 >> 2) * 40 + (wi1 & 3) * 8] = wk1;
        *(uint4*)&Wvs[(wi0 >> 2) * 40 + (wi0 & 3) * 8] = wv0;
        *(uint4*)&Wvs[(wi1 >> 2) * 40 + (wi1 & 3) * 8] = wv1;
      }
      __syncthreads();
      if (s < 8) {
        const int k0 = (s + 1) * 32;
#pragma unroll
        for (int i = 0; i < 8; ++i) {
          const int idx = t + 256 * i;
          const int r = idx >> 5, k = k0 + (idx & 31);
          yr[i] = (k < DYK) ? Y[(size_t)(row0 + r) * DYK + k] : 0.f;
        }
        if (t < 160) {
          wk0 = *(const uint4*)&Wtk[(wi0 >> 2) * DYKP + k0 + (wi0 & 3) * 8];
          wk1 = *(const uint4*)&Wtk[(wi1 >> 2) * DYKP + k0 + (wi1 & 3) * 8];
          wv0 = *(const uint4*)&Wtv[(wi0 >> 2) * DYKP + k0 + (wi0 & 3) * 8];
          wv1 = *(const uint4*)&Wtv[(wi1 >> 2) * DYKP + k0 + (wi1 & 3) * 8];
        }
      }
      const half8v a = *(const half8v*)&Ys[(wv * 16 + m16) * 40 + quad * 8];
#pragma unroll
      for (int nt = 0; nt < 5; ++nt) {
        const half8v bk = *(const half8v*)&Wks[(nt * 16 + m16) * 40 + quad * 8];
        ak[nt] = __builtin_amdgcn_mfma_f32_16x16x32_f16(a, bk, ak[nt], 0, 0, 0);
        const half8v bv = *(const half8v*)&Wvs[(nt * 16 + m16) * 40 + quad * 8];
        av[nt] = __builtin_amdgcn_mfma_f32_16x16x32_f16(a, bv, av[nt], 0, 0, 0);
      }
    }
#pragma unroll
    for (int nt = 0; nt < 5; ++nt) {
      const int col = nt * 16 + m16;
      const int h = col / 10, d = col - h * 10;
#pragma unroll
      for (int p = 0; p < 4; ++p) {
        const int grow = row0 + wv * 16 + quad * 4 + p;
        const int bb = grow >> 9, ny = grow & 511;
        const size_t o = (((size_t)bb * NHEAD + h) * NYS + ny) * DHEAD + d;
        Kw[o] = (f16)ak[nt][p];
        Vw[o] = (f16)av[nt][p];
      }
    }
  }
}

// =====================================================================
// attn v2: 4 blocks per (b,h) (grid 2048), 4 waves, 2 q-tiles/wave.
// LDS shrunk 39.2KB -> 30.9KB (Ks stride 22->20 halves; Vt 16->10 rows,
// output cols 10..15 alias valid rows -- those cols are never written)
// -> 5 resident blocks/CU (was 4) and 2x block-level parallelism.
// Dual accumulators; no-max softmax, q pre-scaled.
// =====================================================================
#define KSTR 20
#define VSTR 522

__global__ __launch_bounds__(256) void attn(const f16* __restrict__ Q,
                                            const f16* __restrict__ K,
                                            const f16* __restrict__ V,
                                            float* __restrict__ O) {
  __shared__ f16 Ks[512 * KSTR];   // [key][d], d 10..15 zeroed
  __shared__ f16 Vt[10 * VSTR];    // [d][key], d = 0..9 only
  const int t = threadIdx.x;
  const int wv = t >> 6, lane = t & 63, m16 = lane & 15, quad = lane >> 4;
  const int bh = blockIdx.x >> 2, quarter = blockIdx.x & 3;
  const int b = bh >> 3, h = bh & 7;

  const u32* Kg = (const u32*)K + (size_t)bh * NYS * 5;
  const u32* Vg = (const u32*)V + (size_t)bh * NYS * 5;
  for (int idx = t; idx < 2560; idx += 256) {
    const u32 row = (u32)idx / 5u, c = (u32)idx - row * 5u;
    const half2v kv = __builtin_bit_cast(half2v, Kg[idx]);
    Ks[row * KSTR + 2 * c]     = kv[0];
    Ks[row * KSTR + 2 * c + 1] = kv[1];
    const half2v vvv = __builtin_bit_cast(half2v, Vg[idx]);
    Vt[(2 * c) * VSTR + row]     = vvv[0];
    Vt[(2 * c + 1) * VSTR + row] = vvv[1];
  }
  for (int idx = t; idx < 3072; idx += 256) {  // Ks d-pad 10..15
    const u32 row = (u32)idx / 6u, d = 10u + ((u32)idx - row * 6u);
    Ks[row * KSTR + d] = (f16)0.f;
  }
  __syncthreads();

  const int vrow = (m16 < DHEAD) ? m16 : (m16 - DHEAD);  // alias dead cols
  const float scale = 0.31622776601683794f;  // 1/sqrt(10)
#pragma unroll 1
  for (int i = 0; i < 2; ++i) {
    const int qt = quarter * 8 + wv * 2 + i;
    const int qrow = qt * 16 + m16;
    const u32* Qg32 = (const u32*)(Q + ((size_t)b * NXS + qrow) * DMODEL + h * DHEAD);
    float s0 = 0.f, s1 = 0.f, s2 = 0.f, s3 = 0.f;
    if (quad < 2) {
      const u32 ua = Qg32[quad * 2], ub = Qg32[quad * 2 + 1];
      const half2v ha = __builtin_bit_cast(half2v, ua);
      const half2v hb = __builtin_bit_cast(half2v, ub);
      s0 = (float)ha[0]; s1 = (float)ha[1]; s2 = (float)hb[0]; s3 = (float)hb[1];
    } else if (quad == 2) {
      const u32 ua = Qg32[4];
      const half2v ha = __builtin_bit_cast(half2v, ua);
      s0 = (float)ha[0]; s1 = (float)ha[1];
    }
    const half4v qf = __builtin_shufflevector(pk2(s0 * scale, s1 * scale),
                                              pk2(s2 * scale, s3 * scale),
                                              0, 1, 2, 3);
    floatx4 o0 = (floatx4){0.f, 0.f, 0.f, 0.f};
    floatx4 o1 = (floatx4){0.f, 0.f, 0.f, 0.f};
    float l0 = 0.f, l1 = 0.f;
    for (int kt = 0; kt < 32; kt += 2) {
#pragma unroll
      for (int u = 0; u < 2; ++u) {
        const int ktu = kt + u;
        const int kb = (ktu * 16 + m16) * KSTR + quad * 4;
        const half4v kf = h4u32(*(const u32*)&Ks[kb], *(const u32*)&Ks[kb + 2]);
        const floatx4 s = __builtin_amdgcn_mfma_f32_16x16x16f16(
            kf, qf, (floatx4){0.f, 0.f, 0.f, 0.f}, 0, 0, 0);
        const float p0 = __expf(s[0]);
        const float p1 = __expf(s[1]);
        const float p2 = __expf(s[2]);
        const float p3 = __expf(s[3]);
        const half4v pf = __builtin_shufflevector(pk2(p0, p1), pk2(p2, p3),
                                                  0, 1, 2, 3);
        const int vb = vrow * VSTR + ktu * 16 + quad * 4;
        const half4v vf = h4u32(*(const u32*)&Vt[vb], *(const u32*)&Vt[vb + 2]);
        if (u == 0) {
          l0 += (p0 + p1) + (p2 + p3);
          o0 = __builtin_amdgcn_mfma_f32_16x16x16f16(pf, vf, o0, 0, 0, 0);
        } else {
          l1 += (p0 + p1) + (p2 + p3);
          o1 = __builtin_amdgcn_mfma_f32_16x16x16f16(pf, vf, o1, 0, 0, 0);
        }
      }
    }
    float lp = l0 + l1;
    lp += __shfl_xor(lp, 16);
    lp += __shfl_xor(lp, 32);
#pragma unroll
    for (int p = 0; p < 4; ++p) {
      const int rq = qt * 16 + quad * 4 + p;
      const float lr = __shfl(lp, quad * 4 + p);
      if (m16 < DHEAD) {
        const float qres = (float)Q[((size_t)b * NXS + rq) * DMODEL + h * DHEAD + m16];
        O[((size_t)b * NXS + rq) * DMODEL + h * DHEAD + m16] =
            qres + (o0[p] + o1[p]) / lr;
      }
    }
  }
}

extern "C" void kernel_launch(void* const* d_in, const int* in_sizes, int n_in,
                              void* d_out, int out_size, void* d_ws, size_t ws_size,
                              hipStream_t stream) {
  const float* x  = (const float*)d_in[0];
  const float* y  = (const float*)d_in[1];
  const float* Wq = (const float*)d_in[2];
  const float* Wk = (const float*)d_in[3];
  const float* Wv = (const float*)d_in[4];
  float* out = (float*)d_out;

  char* ws = (char*)d_ws;
  f16* Wtq = (f16*)(ws);                  // 80*768*2  = 122880 B
  f16* Wtk = (f16*)(ws + 122880);         // 80*288*2  =  46080 B
  f16* Wtv = (f16*)(ws + 168960);         // 46080 B
  f16* Qw  = (f16*)(ws + 262144);         // 5242880 B
  f16* Kw  = (f16*)(ws + 5505024);
  f16* Vw  = (f16*)(ws + 10747904);

  w_prep<<<240, 256, 0, stream>>>(Wq, Wk, Wv, Wtq, Wtk, Wtv);
  proj  <<<1024, 256, 0, stream>>>(x, y, Wtq, Wtk, Wtv, Qw, Kw, Vw);
  attn  <<<2048, 256, 0, stream>>>(Qw, Kw, Vw, out);
}

// Round 4
// 250.116 us; speedup vs baseline: 1.1212x; 1.0230x over previous
//
#include <hip/hip_runtime.h>
#include <stdint.h>

typedef unsigned short u16;
typedef unsigned int   u32;
typedef _Float16       f16;

typedef __attribute__((ext_vector_type(2))) _Float16 half2v;
typedef __attribute__((ext_vector_type(4))) _Float16 half4v;
typedef __attribute__((ext_vector_type(8))) _Float16 half8v;
typedef __attribute__((ext_vector_type(4))) float    floatx4;

#define NXS    512
#define NYS    512
#define NHEAD  8
#define DHEAD  10
#define DMODEL 80
#define DXK    768
#define DYK    283
#define DYKP   288   // padded

__device__ inline half2v pk2(float x, float y) {
  return __builtin_bit_cast(half2v, __builtin_amdgcn_cvt_pkrtz(x, y));
}
__device__ inline half4v cvt4(float4 v) {
  return __builtin_shufflevector(pk2(v.x, v.y), pk2(v.z, v.w), 0, 1, 2, 3);
}
__device__ inline half4v h4u32(u32 a, u32 b) {
  return __builtin_shufflevector(__builtin_bit_cast(half2v, a),
                                 __builtin_bit_cast(half2v, b), 0, 1, 2, 3);
}

// =====================================================================
// w_prep: transpose + fp32->f16 weights. Tq[c][k] (80x768),
// Tk/Tv[c][k] (80x288, zero-padded past k=283).  (v1 exact)
// =====================================================================
__global__ __launch_bounds__(256) void w_prep(const float* __restrict__ Wq,
                                              const float* __restrict__ Wk,
                                              const float* __restrict__ Wv,
                                              f16* __restrict__ Tq,
                                              f16* __restrict__ Tk,
                                              f16* __restrict__ Tv) {
  const int idx = blockIdx.x * 256 + threadIdx.x;
  if (idx < 80 * 768) {
    const int c = idx / 768, k = idx - c * 768;
    Tq[idx] = (f16)Wq[k * 80 + c];
  }
  if (idx < 80 * 288) {
    const int c = idx / 288, k = idx - c * 288;
    float a = 0.f, b = 0.f;
    if (k < DYK) { a = Wk[k * 80 + c]; b = Wv[k * 80 + c]; }
    Tk[idx] = (f16)a;
    Tv[idx] = (f16)b;
  }
}

// =====================================================================
// proj v5: v1 tiles/layout/numerics EXACTLY, plus:
//  - ping-pong double-buffered LDS (one __syncthreads per K-step,
//    was two) -- union'd single smem array, 35.8KB -> 4 blocks/CU,
//    grid 1024 fully resident.
//  - 2-deep register prefetch: load(s+2) issued BEFORE the
//    vmcnt-blocking store of step s+1's data, so the wait distance is
//    a full step (compute+store+barrier) instead of one barrier.
//  - path split stays blk<512 (XCD-balanced under blk%8 round-robin;
//    parity split anti-correlates with XCDs -- round-3 lesson).
//  - launch_bounds(256,4) pins VGPR<=128 (Q ~70, KV ~110 est).
// =====================================================================
__global__ __launch_bounds__(256, 4) void proj(const float* __restrict__ X,
                                               const float* __restrict__ Y,
                                               const f16* __restrict__ Wtq,
                                               const f16* __restrict__ Wtk,
                                               const f16* __restrict__ Wtv,
                                               f16* __restrict__ Qw,
                                               f16* __restrict__ Kw,
                                               f16* __restrict__ Vw) {
  __shared__ f16 smem[2 * 8960];   // 2 buffers x (64*40 + 80*40 + 80*40) f16
  const int t = threadIdx.x;
  const int wv = t >> 6, lane = t & 63, m16 = lane & 15, quad = lane >> 4;
  const int blk = blockIdx.x;

  if (blk < 512) {
    // ---------------- Q path: 24 steps of K=32 ----------------
    const int row0 = blk * 64;
    const int xr_r = t >> 3, xr_k = (t & 7) << 2;   // rows 0..31, +32 pair
    const int wi0 = t, wi1 = t + 160;
    f16* const bufQ0 = smem;
    f16* const bufQ1 = smem + 8960;

    float4 xa0, xa1, xb0, xb1;
    uint4 wa0, wa1, wb0, wb1;

#define Q_LOAD(X0, X1, W0, W1, S)                                              \
    do {                                                                       \
      const int k0_ = (S) * 32;                                                \
      X0 = *(const float4*)&X[(size_t)(row0 + xr_r) * DXK + k0_ + xr_k];       \
      X1 = *(const float4*)&X[(size_t)(row0 + xr_r + 32) * DXK + k0_ + xr_k];  \
      if (t < 160) {                                                           \
        W0 = *(const uint4*)&Wtq[(wi0 >> 2) * DXK + k0_ + (wi0 & 3) * 8];      \
        W1 = *(const uint4*)&Wtq[(wi1 >> 2) * DXK + k0_ + (wi1 & 3) * 8];      \
      }                                                                        \
    } while (0)

#define Q_STORE(BUF, X0, X1, W0, W1)                                           \
    do {                                                                       \
      f16* const Xs_ = (BUF);                                                  \
      f16* const Ws_ = (BUF) + 2560;                                           \
      *(half4v*)&Xs_[xr_r * 40 + xr_k] = cvt4(X0);                             \
      *(half4v*)&Xs_[(xr_r + 32) * 40 + xr_k] = cvt4(X1);                      \
      if (t < 160) {                                                           \
        *(uint4*)&Ws_[(wi0 >> 2) * 40 + (wi0 & 3) * 8] = W0;                   \
        *(uint4*)&Ws_[(wi1 >> 2) * 40 + (wi1 & 3) * 8] = W1;                   \
      }                                                                        \
    } while (0)

#define Q_COMPUTE(BUF)                                                         \
    do {                                                                       \
      f16* const Xs_ = (BUF);                                                  \
      f16* const Ws_ = (BUF) + 2560;                                           \
      const half8v a = *(const half8v*)&Xs_[(wv * 16 + m16) * 40 + quad * 8];  \
      _Pragma("unroll")                                                        \
      for (int nt = 0; nt < 5; ++nt) {                                         \
        const half8v b = *(const half8v*)&Ws_[(nt * 16 + m16) * 40 + quad * 8];\
        acc[nt] = __builtin_amdgcn_mfma_f32_16x16x32_f16(a, b, acc[nt], 0, 0, 0); \
      }                                                                        \
    } while (0)

    floatx4 acc[5];
#pragma unroll
    for (int i = 0; i < 5; ++i) acc[i] = (floatx4){0.f, 0.f, 0.f, 0.f};

    Q_LOAD(xa0, xa1, wa0, wa1, 0);
    Q_LOAD(xb0, xb1, wb0, wb1, 1);
    Q_STORE(bufQ0, xa0, xa1, wa0, wa1);
    __syncthreads();

    for (int s = 0; s < 24; s += 2) {
      // even step s: compute buf0; issue load(s+2)->A; store buf1 <- B (s+1)
      Q_COMPUTE(bufQ0);
      if (s + 2 < 24) Q_LOAD(xa0, xa1, wa0, wa1, s + 2);
      Q_STORE(bufQ1, xb0, xb1, wb0, wb1);
      __syncthreads();
      // odd step s+1: compute buf1; issue load(s+3)->B; store buf0 <- A (s+2)
      Q_COMPUTE(bufQ1);
      if (s + 3 < 24) Q_LOAD(xb0, xb1, wb0, wb1, s + 3);
      if (s + 2 < 24) Q_STORE(bufQ0, xa0, xa1, wa0, wa1);
      __syncthreads();
    }

#pragma unroll
    for (int nt = 0; nt < 5; ++nt) {
      const int col = nt * 16 + m16;
#pragma unroll
      for (int p = 0; p < 4; ++p) {
        const int grow = row0 + wv * 16 + quad * 4 + p;
        Qw[(size_t)grow * DMODEL + col] = (f16)acc[nt][p];
      }
    }
  } else {
    // ---------------- KV path: 9 steps of K=32 ----------------
    const int row0 = (blk - 512) * 64;
    const int wi0 = t, wi1 = t + 160;
    f16* const bufK0 = smem;
    f16* const bufK1 = smem + 8960;

    float ya[8], yb[8];
    uint4 wka0, wka1, wva0, wva1, wkb0, wkb1, wvb0, wvb1;

#define KV_LOAD(YR, WK0, WK1, WV0, WV1, S)                                     \
    do {                                                                       \
      const int k0_ = (S) * 32;                                                \
      _Pragma("unroll")                                                        \
      for (int i = 0; i < 8; ++i) {                                            \
        const int idx = t + 256 * i;                                           \
        const int r = idx >> 5, k = k0_ + (idx & 31);                          \
        YR[i] = (k < DYK) ? Y[(size_t)(row0 + r) * DYK + k] : 0.f;             \
      }                                                                        \
      if (t < 160) {                                                           \
        WK0 = *(const uint4*)&Wtk[(wi0 >> 2) * DYKP + k0_ + (wi0 & 3) * 8];    \
        WK1 = *(const uint4*)&Wtk[(wi1 >> 2) * DYKP + k0_ + (wi1 & 3) * 8];    \
        WV0 = *(const uint4*)&Wtv[(wi0 >> 2) * DYKP + k0_ + (wi0 & 3) * 8];    \
        WV1 = *(const uint4*)&Wtv[(wi1 >> 2) * DYKP + k0_ + (wi1 & 3) * 8];    \
      }                                                                        \
    } while (0)

#define KV_STORE(BUF, YR, WK0, WK1, WV0, WV1)                                  \
    do {                                                                       \
      f16* const Ys_  = (BUF);                                                 \
      f16* const Wks_ = (BUF) + 2560;                                          \
      f16* const Wvs_ = (BUF) + 5760;                                          \
      _Pragma("unroll")                                                        \
      for (int i = 0; i < 8; ++i) {                                            \
        const int idx = t + 256 * i;                                           \
        Ys_[(idx >> 5) * 40 + (idx & 31)] = (f16)YR[i];                        \
      }                                                                        \
      if (t < 160) {                                                           \
        *(uint4*)&Wks_[(wi0 >> 2) * 40 + (wi0 & 3) * 8] = WK0;                 \
        *(uint4*)&Wks_[(wi1 >> 2) * 40 + (wi1 & 3) * 8] = WK1;                 \
        *(uint4*)&Wvs_[(wi0 >> 2) * 40 + (wi0 & 3) * 8] = WV0;                 \
        *(uint4*)&Wvs_[(wi1 >> 2) * 40 + (wi1 & 3) * 8] = WV1;                 \
      }                                                                        \
    } while (0)

#define KV_COMPUTE(BUF)                                                        \
    do {                                                                       \
      f16* const Ys_  = (BUF);                                                 \
      f16* const Wks_ = (BUF) + 2560;                                          \
      f16* const Wvs_ = (BUF) + 5760;                                          \
      const half8v a = *(const half8v*)&Ys_[(wv * 16 + m16) * 40 + quad * 8];  \
      _Pragma("unroll")                                                        \
      for (int nt = 0; nt < 5; ++nt) {                                         \
        const half8v bk = *(const half8v*)&Wks_[(nt * 16 + m16) * 40 + quad * 8]; \
        ak[nt] = __builtin_amdgcn_mfma_f32_16x16x32_f16(a, bk, ak[nt], 0, 0, 0); \
        const half8v bv = *(const half8v*)&Wvs_[(nt * 16 + m16) * 40 + quad * 8]; \
        av[nt] = __builtin_amdgcn_mfma_f32_16x16x32_f16(a, bv, av[nt], 0, 0, 0); \
      }                                                                        \
    } while (0)

    floatx4 ak[5], av[5];
#pragma unroll
    for (int i = 0; i < 5; ++i) {
      ak[i] = (floatx4){0.f, 0.f, 0.f, 0.f};
      av[i] = (floatx4){0.f, 0.f, 0.f, 0.f};
    }

    KV_LOAD(ya, wka0, wka1, wva0, wva1, 0);
    KV_LOAD(yb, wkb0, wkb1, wvb0, wvb1, 1);
    KV_STORE(bufK0, ya, wka0, wka1, wva0, wva1);
    __syncthreads();

    for (int s = 0; s < 8; s += 2) {
      KV_COMPUTE(bufK0);
      if (s + 2 < 9) KV_LOAD(ya, wka0, wka1, wva0, wva1, s + 2);
      KV_STORE(bufK1, yb, wkb0, wkb1, wvb0, wvb1);
      __syncthreads();
      KV_COMPUTE(bufK1);
      if (s + 3 < 9) KV_LOAD(yb, wkb0, wkb1, wvb0, wvb1, s + 3);
      if (s + 2 < 9) KV_STORE(bufK0, ya, wka0, wka1, wva0, wva1);
      __syncthreads();
    }
    KV_COMPUTE(bufK0);   // step 8 (stored during s=6 iteration's odd phase)

#pragma unroll
    for (int nt = 0; nt < 5; ++nt) {
      const int col = nt * 16 + m16;
      const int h = col / 10, d = col - h * 10;
#pragma unroll
      for (int p = 0; p < 4; ++p) {
        const int grow = row0 + wv * 16 + quad * 4 + p;
        const int bb = grow >> 9, ny = grow & 511;
        const size_t o = (((size_t)bb * NHEAD + h) * NYS + ny) * DHEAD + d;
        Kw[o] = (f16)ak[nt][p];
        Vw[o] = (f16)av[nt][p];
      }
    }
  }
}

// =====================================================================
// attn: v1 EXACT. 2 blocks per (b,h) (grid 1024), 4 waves, 4 q-tiles/wave.
// K,V^T in LDS (odd-dword strides 22 / 522); Q frags + residual direct
// from global. Dual accumulators; no-max softmax, q pre-scaled.
// =====================================================================
__global__ __launch_bounds__(256) void attn(const f16* __restrict__ Q,
                                            const f16* __restrict__ K,
                                            const f16* __restrict__ V,
                                            float* __restrict__ O) {
  __shared__ f16 Ks[512 * 22];   // [key][d], d 10..15 zeroed
  __shared__ f16 Vt[16 * 522];   // [d][key], d rows 10..15 zeroed
  const int t = threadIdx.x;
  const int wv = t >> 6, lane = t & 63, m16 = lane & 15, quad = lane >> 4;
  const int bh = blockIdx.x >> 1, half = blockIdx.x & 1;
  const int b = bh >> 3, h = bh & 7;

  const u32* Kg = (const u32*)K + (size_t)bh * NYS * 5;
  const u32* Vg = (const u32*)V + (size_t)bh * NYS * 5;
  for (int idx = t; idx < 2560; idx += 256) {
    const u32 row = (u32)idx / 5u, c = (u32)idx - row * 5u;
    const half2v kv = __builtin_bit_cast(half2v, Kg[idx]);
    Ks[row * 22 + 2 * c]     = kv[0];
    Ks[row * 22 + 2 * c + 1] = kv[1];
    const half2v vvv = __builtin_bit_cast(half2v, Vg[idx]);
    Vt[(2 * c) * 522 + row]     = vvv[0];
    Vt[(2 * c + 1) * 522 + row] = vvv[1];
  }
  for (int idx = t; idx < 3072; idx += 256) {  // Ks d-pad 10..15
    const u32 row = (u32)idx / 6u, d = 10u + ((u32)idx - row * 6u);
    Ks[row * 22 + d] = (f16)0.f;
  }
  for (int idx = t; idx < 6 * 522; idx += 256)  // Vt rows 10..15
    Vt[10 * 522 + idx] = (f16)0.f;
  __syncthreads();

  const float scale = 0.31622776601683794f;  // 1/sqrt(10)
#pragma unroll 1
  for (int i = 0; i < 4; ++i) {
    const int qt = half * 16 + wv * 4 + i;
    const int qrow = qt * 16 + m16;
    const u32* Qg32 = (const u32*)(Q + ((size_t)b * NXS + qrow) * DMODEL + h * DHEAD);
    float s0 = 0.f, s1 = 0.f, s2 = 0.f, s3 = 0.f;
    if (quad < 2) {
      const u32 ua = Qg32[quad * 2], ub = Qg32[quad * 2 + 1];
      const half2v ha = __builtin_bit_cast(half2v, ua);
      const half2v hb = __builtin_bit_cast(half2v, ub);
      s0 = (float)ha[0]; s1 = (float)ha[1]; s2 = (float)hb[0]; s3 = (float)hb[1];
    } else if (quad == 2) {
      const u32 ua = Qg32[4];
      const half2v ha = __builtin_bit_cast(half2v, ua);
      s0 = (float)ha[0]; s1 = (float)ha[1];
    }
    const half4v qf = __builtin_shufflevector(pk2(s0 * scale, s1 * scale),
                                              pk2(s2 * scale, s3 * scale),
                                              0, 1, 2, 3);
    floatx4 o0 = (floatx4){0.f, 0.f, 0.f, 0.f};
    floatx4 o1 = (floatx4){0.f, 0.f, 0.f, 0.f};
    float l0 = 0.f, l1 = 0.f;
    for (int kt = 0; kt < 32; kt += 2) {
#pragma unroll
      for (int u = 0; u < 2; ++u) {
        const int ktu = kt + u;
        const int kb = (ktu * 16 + m16) * 22 + quad * 4;
        const half4v kf = h4u32(*(const u32*)&Ks[kb], *(const u32*)&Ks[kb + 2]);
        const floatx4 s = __builtin_amdgcn_mfma_f32_16x16x16f16(
            kf, qf, (floatx4){0.f, 0.f, 0.f, 0.f}, 0, 0, 0);
        const float p0 = __expf(s[0]);
        const float p1 = __expf(s[1]);
        const float p2 = __expf(s[2]);
        const float p3 = __expf(s[3]);
        const half4v pf = __builtin_shufflevector(pk2(p0, p1), pk2(p2, p3),
                                                  0, 1, 2, 3);
        const int vb = m16 * 522 + ktu * 16 + quad * 4;
        const half4v vf = h4u32(*(const u32*)&Vt[vb], *(const u32*)&Vt[vb + 2]);
        if (u == 0) {
          l0 += (p0 + p1) + (p2 + p3);
          o0 = __builtin_amdgcn_mfma_f32_16x16x16f16(pf, vf, o0, 0, 0, 0);
        } else {
          l1 += (p0 + p1) + (p2 + p3);
          o1 = __builtin_amdgcn_mfma_f32_16x16x16f16(pf, vf, o1, 0, 0, 0);
        }
      }
    }
    float lp = l0 + l1;
    lp += __shfl_xor(lp, 16);
    lp += __shfl_xor(lp, 32);
#pragma unroll
    for (int p = 0; p < 4; ++p) {
      const int rq = qt * 16 + quad * 4 + p;
      const float lr = __shfl(lp, quad * 4 + p);
      if (m16 < DHEAD) {
        const float qres = (float)Q[((size_t)b * NXS + rq) * DMODEL + h * DHEAD + m16];
        O[((size_t)b * NXS + rq) * DMODEL + h * DHEAD + m16] =
            qres + (o0[p] + o1[p]) / lr;
      }
    }
  }
}

extern "C" void kernel_launch(void* const* d_in, const int* in_sizes, int n_in,
                              void* d_out, int out_size, void* d_ws, size_t ws_size,
                              hipStream_t stream) {
  const float* x  = (const float*)d_in[0];
  const float* y  = (const float*)d_in[1];
  const float* Wq = (const float*)d_in[2];
  const float* Wk = (const float*)d_in[3];
  const float* Wv = (const float*)d_in[4];
  float* out = (float*)d_out;

  char* ws = (char*)d_ws;
  f16* Wtq = (f16*)(ws);                  // 80*768*2  = 122880 B
  f16* Wtk = (f16*)(ws + 122880);         // 80*288*2  =  46080 B
  f16* Wtv = (f16*)(ws + 168960);         // 46080 B
  f16* Qw  = (f16*)(ws + 262144);         // 5242880 B
  f16* Kw  = (f16*)(ws + 5505024);
  f16* Vw  = (f16*)(ws + 10747904);

  w_prep<<<240, 256, 0, stream>>>(Wq, Wk, Wv, Wtq, Wtk, Wtv);
  proj  <<<1024, 256, 0, stream>>>(x, y, Wtq, Wtk, Wtv, Qw, Kw, Vw);
  attn  <<<1024, 256, 0, stream>>>(Qw, Kw, Vw, out);
}

// Round 5
// 242.236 us; speedup vs baseline: 1.1577x; 1.0325x over previous
//
#include <hip/hip_runtime.h>
#include <stdint.h>

typedef unsigned short u16;
typedef unsigned int   u32;
typedef _Float16       f16;

typedef __attribute__((ext_vector_type(2))) _Float16 half2v;
typedef __attribute__((ext_vector_type(4))) _Float16 half4v;
typedef __attribute__((ext_vector_type(8))) _Float16 half8v;
typedef __attribute__((ext_vector_type(4))) float    floatx4;

#define NXS    512
#define NYS    512
#define NHEAD  8
#define DHEAD  10
#define DMODEL 80
#define DXK    768
#define DYK    283
#define DYKP   288   // padded

__device__ inline half2v pk2(float x, float y) {
  return __builtin_bit_cast(half2v, __builtin_amdgcn_cvt_pkrtz(x, y));
}
__device__ inline half4v cvt4(float4 v) {
  return __builtin_shufflevector(pk2(v.x, v.y), pk2(v.z, v.w), 0, 1, 2, 3);
}
__device__ inline half4v h4u32(u32 a, u32 b) {
  return __builtin_shufflevector(__builtin_bit_cast(half2v, a),
                                 __builtin_bit_cast(half2v, b), 0, 1, 2, 3);
}

// =====================================================================
// w_prep: transpose + fp32->f16 weights. Tq[c][k] (80x768),
// Tk/Tv[c][k] (80x288, zero-padded past k=283).  (v1 exact)
// =====================================================================
__global__ __launch_bounds__(256) void w_prep(const float* __restrict__ Wq,
                                              const float* __restrict__ Wk,
                                              const float* __restrict__ Wv,
                                              f16* __restrict__ Tq,
                                              f16* __restrict__ Tk,
                                              f16* __restrict__ Tv) {
  const int idx = blockIdx.x * 256 + threadIdx.x;
  if (idx < 80 * 768) {
    const int c = idx / 768, k = idx - c * 768;
    Tq[idx] = (f16)Wq[k * 80 + c];
  }
  if (idx < 80 * 288) {
    const int c = idx / 288, k = idx - c * 288;
    float a = 0.f, b = 0.f;
    if (k < DYK) { a = Wk[k * 80 + c]; b = Wv[k * 80 + c]; }
    Tk[idx] = (f16)a;
    Tv[idx] = (f16)b;
  }
}

// =====================================================================
// proj v6: v5's ping-pong pipeline, spill-free.
// ONLY change vs v5: plain __launch_bounds__(256). Empirical rule from
// rounds 1/2/4: the ",4" second arg caps the allocator at 64 arch
// VGPRs on this toolchain -> KV live set (~110 regs) spills to scratch
// (WRITE_SIZE 15.4->43 MB signature). LDS 35.8KB already caps
// residency at 4 blocks/CU, so no occupancy downside.
//  - ping-pong double-buffered LDS: ONE __syncthreads per K-step.
//  - 2-deep register prefetch: load(s+2) issued before the
//    vmcnt-blocking store of step s+1's data.
//  - path split blk<512 (XCD-balanced under blk%8 round-robin;
//    parity split anti-correlates with XCDs -- round-3 lesson).
// =====================================================================
__global__ __launch_bounds__(256) void proj(const float* __restrict__ X,
                                            const float* __restrict__ Y,
                                            const f16* __restrict__ Wtq,
                                            const f16* __restrict__ Wtk,
                                            const f16* __restrict__ Wtv,
                                            f16* __restrict__ Qw,
                                            f16* __restrict__ Kw,
                                            f16* __restrict__ Vw) {
  __shared__ f16 smem[2 * 8960];   // 2 buffers x (64*40 + 80*40 + 80*40) f16
  const int t = threadIdx.x;
  const int wv = t >> 6, lane = t & 63, m16 = lane & 15, quad = lane >> 4;
  const int blk = blockIdx.x;

  if (blk < 512) {
    // ---------------- Q path: 24 steps of K=32 ----------------
    const int row0 = blk * 64;
    const int xr_r = t >> 3, xr_k = (t & 7) << 2;   // rows 0..31, +32 pair
    const int wi0 = t, wi1 = t + 160;
    f16* const bufQ0 = smem;
    f16* const bufQ1 = smem + 8960;

    float4 xa0, xa1, xb0, xb1;
    uint4 wa0, wa1, wb0, wb1;

#define Q_LOAD(X0, X1, W0, W1, S)                                              \
    do {                                                                       \
      const int k0_ = (S) * 32;                                                \
      X0 = *(const float4*)&X[(size_t)(row0 + xr_r) * DXK + k0_ + xr_k];       \
      X1 = *(const float4*)&X[(size_t)(row0 + xr_r + 32) * DXK + k0_ + xr_k];  \
      if (t < 160) {                                                           \
        W0 = *(const uint4*)&Wtq[(wi0 >> 2) * DXK + k0_ + (wi0 & 3) * 8];      \
        W1 = *(const uint4*)&Wtq[(wi1 >> 2) * DXK + k0_ + (wi1 & 3) * 8];      \
      }                                                                        \
    } while (0)

#define Q_STORE(BUF, X0, X1, W0, W1)                                           \
    do {                                                                       \
      f16* const Xs_ = (BUF);                                                  \
      f16* const Ws_ = (BUF) + 2560;                                           \
      *(half4v*)&Xs_[xr_r * 40 + xr_k] = cvt4(X0);                             \
      *(half4v*)&Xs_[(xr_r + 32) * 40 + xr_k] = cvt4(X1);                      \
      if (t < 160) {                                                           \
        *(uint4*)&Ws_[(wi0 >> 2) * 40 + (wi0 & 3) * 8] = W0;                   \
        *(uint4*)&Ws_[(wi1 >> 2) * 40 + (wi1 & 3) * 8] = W1;                   \
      }                                                                        \
    } while (0)

#define Q_COMPUTE(BUF)                                                         \
    do {                                                                       \
      f16* const Xs_ = (BUF);                                                  \
      f16* const Ws_ = (BUF) + 2560;                                           \
      const half8v a = *(const half8v*)&Xs_[(wv * 16 + m16) * 40 + quad * 8];  \
      _Pragma("unroll")                                                        \
      for (int nt = 0; nt < 5; ++nt) {                                         \
        const half8v b = *(const half8v*)&Ws_[(nt * 16 + m16) * 40 + quad * 8];\
        acc[nt] = __builtin_amdgcn_mfma_f32_16x16x32_f16(a, b, acc[nt], 0, 0, 0); \
      }                                                                        \
    } while (0)

    floatx4 acc[5];
#pragma unroll
    for (int i = 0; i < 5; ++i) acc[i] = (floatx4){0.f, 0.f, 0.f, 0.f};

    Q_LOAD(xa0, xa1, wa0, wa1, 0);
    Q_LOAD(xb0, xb1, wb0, wb1, 1);
    Q_STORE(bufQ0, xa0, xa1, wa0, wa1);
    __syncthreads();

    for (int s = 0; s < 24; s += 2) {
      // even step s: compute buf0; issue load(s+2)->A; store buf1 <- B (s+1)
      Q_COMPUTE(bufQ0);
      if (s + 2 < 24) Q_LOAD(xa0, xa1, wa0, wa1, s + 2);
      Q_STORE(bufQ1, xb0, xb1, wb0, wb1);
      __syncthreads();
      // odd step s+1: compute buf1; issue load(s+3)->B; store buf0 <- A (s+2)
      Q_COMPUTE(bufQ1);
      if (s + 3 < 24) Q_LOAD(xb0, xb1, wb0, wb1, s + 3);
      if (s + 2 < 24) Q_STORE(bufQ0, xa0, xa1, wa0, wa1);
      __syncthreads();
    }

#pragma unroll
    for (int nt = 0; nt < 5; ++nt) {
      const int col = nt * 16 + m16;
#pragma unroll
      for (int p = 0; p < 4; ++p) {
        const int grow = row0 + wv * 16 + quad * 4 + p;
        Qw[(size_t)grow * DMODEL + col] = (f16)acc[nt][p];
      }
    }
  } else {
    // ---------------- KV path: 9 steps of K=32 ----------------
    const int row0 = (blk - 512) * 64;
    const int wi0 = t, wi1 = t + 160;
    f16* const bufK0 = smem;
    f16* const bufK1 = smem + 8960;

    float ya[8], yb[8];
    uint4 wka0, wka1, wva0, wva1, wkb0, wkb1, wvb0, wvb1;

#define KV_LOAD(YR, WK0, WK1, WV0, WV1, S)                                     \
    do {                                                                       \
      const int k0_ = (S) * 32;                                                \
      _Pragma("unroll")                                                        \
      for (int i = 0; i < 8; ++i) {                                            \
        const int idx = t + 256 * i;                                           \
        const int r = idx >> 5, k = k0_ + (idx & 31);                          \
        YR[i] = (k < DYK) ? Y[(size_t)(row0 + r) * DYK + k] : 0.f;             \
      }                                                                        \
      if (t < 160) {                                                           \
        WK0 = *(const uint4*)&Wtk[(wi0 >> 2) * DYKP + k0_ + (wi0 & 3) * 8];    \
        WK1 = *(const uint4*)&Wtk[(wi1 >> 2) * DYKP + k0_ + (wi1 & 3) * 8];    \
        WV0 = *(const uint4*)&Wtv[(wi0 >> 2) * DYKP + k0_ + (wi0 & 3) * 8];    \
        WV1 = *(const uint4*)&Wtv[(wi1 >> 2) * DYKP + k0_ + (wi1 & 3) * 8];    \
      }                                                                        \
    } while (0)

#define KV_STORE(BUF, YR, WK0, WK1, WV0, WV1)                                  \
    do {                                                                       \
      f16* const Ys_  = (BUF);                                                 \
      f16* const Wks_ = (BUF) + 2560;                                          \
      f16* const Wvs_ = (BUF) + 5760;                                          \
      _Pragma("unroll")                                                        \
      for (int i = 0; i < 8; ++i) {                                            \
        const int idx = t + 256 * i;                                           \
        Ys_[(idx >> 5) * 40 + (idx & 31)] = (f16)YR[i];                        \
      }                                                                        \
      if (t < 160) {                                                           \
        *(uint4*)&Wks_[(wi0 >> 2) * 40 + (wi0 & 3) * 8] = WK0;                 \
        *(uint4*)&Wks_[(wi1 >> 2) * 40 + (wi1 & 3) * 8] = WK1;                 \
        *(uint4*)&Wvs_[(wi0 >> 2) * 40 + (wi0 & 3) * 8] = WV0;                 \
        *(uint4*)&Wvs_[(wi1 >> 2) * 40 + (wi1 & 3) * 8] = WV1;                 \
      }                                                                        \
    } while (0)

#define KV_COMPUTE(BUF)                                                        \
    do {                                                                       \
      f16* const Ys_  = (BUF);                                                 \
      f16* const Wks_ = (BUF) + 2560;                                          \
      f16* const Wvs_ = (BUF) + 5760;                                          \
      const half8v a = *(const half8v*)&Ys_[(wv * 16 + m16) * 40 + quad * 8];  \
      _Pragma("unroll")                                                        \
      for (int nt = 0; nt < 5; ++nt) {                                         \
        const half8v bk = *(const half8v*)&Wks_[(nt * 16 + m16) * 40 + quad * 8]; \
        ak[nt] = __builtin_amdgcn_mfma_f32_16x16x32_f16(a, bk, ak[nt], 0, 0, 0); \
        const half8v bv = *(const half8v*)&Wvs_[(nt * 16 + m16) * 40 + quad * 8]; \
        av[nt] = __builtin_amdgcn_mfma_f32_16x16x32_f16(a, bv, av[nt], 0, 0, 0); \
      }                                                                        \
    } while (0)

    floatx4 ak[5], av[5];
#pragma unroll
    for (int i = 0; i < 5; ++i) {
      ak[i] = (floatx4){0.f, 0.f, 0.f, 0.f};
      av[i] = (floatx4){0.f, 0.f, 0.f, 0.f};
    }

    KV_LOAD(ya, wka0, wka1, wva0, wva1, 0);
    KV_LOAD(yb, wkb0, wkb1, wvb0, wvb1, 1);
    KV_STORE(bufK0, ya, wka0, wka1, wva0, wva1);
    __syncthreads();

    for (int s = 0; s < 8; s += 2) {
      KV_COMPUTE(bufK0);
      if (s + 2 < 9) KV_LOAD(ya, wka0, wka1, wva0, wva1, s + 2);
      KV_STORE(bufK1, yb, wkb0, wkb1, wvb0, wvb1);
      __syncthreads();
      KV_COMPUTE(bufK1);
      if (s + 3 < 9) KV_LOAD(yb, wkb0, wkb1, wvb0, wvb1, s + 3);
      if (s + 2 < 9) KV_STORE(bufK0, ya, wka0, wka1, wva0, wva1);
      __syncthreads();
    }
    KV_COMPUTE(bufK0);   // step 8 (stored during s=6 iteration's odd phase)

#pragma unroll
    for (int nt = 0; nt < 5; ++nt) {
      const int col = nt * 16 + m16;
      const int h = col / 10, d = col - h * 10;
#pragma unroll
      for (int p = 0; p < 4; ++p) {
        const int grow = row0 + wv * 16 + quad * 4 + p;
        const int bb = grow >> 9, ny = grow & 511;
        const size_t o = (((size_t)bb * NHEAD + h) * NYS + ny) * DHEAD + d;
        Kw[o] = (f16)ak[nt][p];
        Vw[o] = (f16)av[nt][p];
      }
    }
  }
}

// =====================================================================
// attn: v1 EXACT. 2 blocks per (b,h) (grid 1024), 4 waves, 4 q-tiles/wave.
// K,V^T in LDS (odd-dword strides 22 / 522); Q frags + residual direct
// from global. Dual accumulators; no-max softmax, q pre-scaled.
// =====================================================================
__global__ __launch_bounds__(256) void attn(const f16* __restrict__ Q,
                                            const f16* __restrict__ K,
                                            const f16* __restrict__ V,
                                            float* __restrict__ O) {
  __shared__ f16 Ks[512 * 22];   // [key][d], d 10..15 zeroed
  __shared__ f16 Vt[16 * 522];   // [d][key], d rows 10..15 zeroed
  const int t = threadIdx.x;
  const int wv = t >> 6, lane = t & 63, m16 = lane & 15, quad = lane >> 4;
  const int bh = blockIdx.x >> 1, half = blockIdx.x & 1;
  const int b = bh >> 3, h = bh & 7;

  const u32* Kg = (const u32*)K + (size_t)bh * NYS * 5;
  const u32* Vg = (const u32*)V + (size_t)bh * NYS * 5;
  for (int idx = t; idx < 2560; idx += 256) {
    const u32 row = (u32)idx / 5u, c = (u32)idx - row * 5u;
    const half2v kv = __builtin_bit_cast(half2v, Kg[idx]);
    Ks[row * 22 + 2 * c]     = kv[0];
    Ks[row * 22 + 2 * c + 1] = kv[1];
    const half2v vvv = __builtin_bit_cast(half2v, Vg[idx]);
    Vt[(2 * c) * 522 + row]     = vvv[0];
    Vt[(2 * c + 1) * 522 + row] = vvv[1];
  }
  for (int idx = t; idx < 3072; idx += 256) {  // Ks d-pad 10..15
    const u32 row = (u32)idx / 6u, d = 10u + ((u32)idx - row * 6u);
    Ks[row * 22 + d] = (f16)0.f;
  }
  for (int idx = t; idx < 6 * 522; idx += 256)  // Vt rows 10..15
    Vt[10 * 522 + idx] = (f16)0.f;
  __syncthreads();

  const float scale = 0.31622776601683794f;  // 1/sqrt(10)
#pragma unroll 1
  for (int i = 0; i < 4; ++i) {
    const int qt = half * 16 + wv * 4 + i;
    const int qrow = qt * 16 + m16;
    const u32* Qg32 = (const u32*)(Q + ((size_t)b * NXS + qrow) * DMODEL + h * DHEAD);
    float s0 = 0.f, s1 = 0.f, s2 = 0.f, s3 = 0.f;
    if (quad < 2) {
      const u32 ua = Qg32[quad * 2], ub = Qg32[quad * 2 + 1];
      const half2v ha = __builtin_bit_cast(half2v, ua);
      const half2v hb = __builtin_bit_cast(half2v, ub);
      s0 = (float)ha[0]; s1 = (float)ha[1]; s2 = (float)hb[0]; s3 = (float)hb[1];
    } else if (quad == 2) {
      const u32 ua = Qg32[4];
      const half2v ha = __builtin_bit_cast(half2v, ua);
      s0 = (float)ha[0]; s1 = (float)ha[1];
    }
    const half4v qf = __builtin_shufflevector(pk2(s0 * scale, s1 * scale),
                                              pk2(s2 * scale, s3 * scale),
                                              0, 1, 2, 3);
    floatx4 o0 = (floatx4){0.f, 0.f, 0.f, 0.f};
    floatx4 o1 = (floatx4){0.f, 0.f, 0.f, 0.f};
    float l0 = 0.f, l1 = 0.f;
    for (int kt = 0; kt < 32; kt += 2) {
#pragma unroll
      for (int u = 0; u < 2; ++u) {
        const int ktu = kt + u;
        const int kb = (ktu * 16 + m16) * 22 + quad * 4;
        const half4v kf = h4u32(*(const u32*)&Ks[kb], *(const u32*)&Ks[kb + 2]);
        const floatx4 s = __builtin_amdgcn_mfma_f32_16x16x16f16(
            kf, qf, (floatx4){0.f, 0.f, 0.f, 0.f}, 0, 0, 0);
        const float p0 = __expf(s[0]);
        const float p1 = __expf(s[1]);
        const float p2 = __expf(s[2]);
        const float p3 = __expf(s[3]);
        const half4v pf = __builtin_shufflevector(pk2(p0, p1), pk2(p2, p3),
                                                  0, 1, 2, 3);
        const int vb = m16 * 522 + ktu * 16 + quad * 4;
        const half4v vf = h4u32(*(const u32*)&Vt[vb], *(const u32*)&Vt[vb + 2]);
        if (u == 0) {
          l0 += (p0 + p1) + (p2 + p3);
          o0 = __builtin_amdgcn_mfma_f32_16x16x16f16(pf, vf, o0, 0, 0, 0);
        } else {
          l1 += (p0 + p1) + (p2 + p3);
          o1 = __builtin_amdgcn_mfma_f32_16x16x16f16(pf, vf, o1, 0, 0, 0);
        }
      }
    }
    float lp = l0 + l1;
    lp += __shfl_xor(lp, 16);
    lp += __shfl_xor(lp, 32);
#pragma unroll
    for (int p = 0; p < 4; ++p) {
      const int rq = qt * 16 + quad * 4 + p;
      const float lr = __shfl(lp, quad * 4 + p);
      if (m16 < DHEAD) {
        const float qres = (float)Q[((size_t)b * NXS + rq) * DMODEL + h * DHEAD + m16];
        O[((size_t)b * NXS + rq) * DMODEL + h * DHEAD + m16] =
            qres + (o0[p] + o1[p]) / lr;
      }
    }
  }
}

extern "C" void kernel_launch(void* const* d_in, const int* in_sizes, int n_in,
                              void* d_out, int out_size, void* d_ws, size_t ws_size,
                              hipStream_t stream) {
  const float* x  = (const float*)d_in[0];
  const float* y  = (const float*)d_in[1];
  const float* Wq = (const float*)d_in[2];
  const float* Wk = (const float*)d_in[3];
  const float* Wv = (const float*)d_in[4];
  float* out = (float*)d_out;

  char* ws = (char*)d_ws;
  f16* Wtq = (f16*)(ws);                  // 80*768*2  = 122880 B
  f16* Wtk = (f16*)(ws + 122880);         // 80*288*2  =  46080 B
  f16* Wtv = (f16*)(ws + 168960);         // 46080 B
  f16* Qw  = (f16*)(ws + 262144);         // 5242880 B
  f16* Kw  = (f16*)(ws + 5505024);
  f16* Vw  = (f16*)(ws + 10747904);

  w_prep<<<240, 256, 0, stream>>>(Wq, Wk, Wv, Wtq, Wtk, Wtv);
  proj  <<<1024, 256, 0, stream>>>(x, y, Wtq, Wtk, Wtv, Qw, Kw, Vw);
  attn  <<<1024, 256, 0, stream>>>(Qw, Kw, Vw, out);
}